// Round 1
// baseline (320.595 us; speedup 1.0000x reference)
//
#include <hip/hip_runtime.h>
#include <hip/hip_bf16.h>

// DeepFM: B=16384, F_DENSE=13, F_SPARSE=26, E=16, V=100000, HID=[512,256]
// Key insight: the MLP is fully affine and only h.sum(axis=1) is used, so the
// whole 2-layer MLP collapses to h0 . w_eff + scalarC (exact algebra).
// Remaining work: one pass over 39 fields per row; 2x26 random 64B gathers.

#define B_     16384
#define FD_    13
#define FS_    26
#define F_     39
#define E_     16
#define V_     100000
#define H1_    512
#define H2_    256
#define DIN_   624
// 1/sqrt(1 + 1e-5) computed in double, cast to float (matches jnp.float32(...))
#define INV_   0.9999950000374998f

// ---------------- precompute kernels ----------------

// v2[i] = sum_j Lw2[i,j] * inv * g2[j]    (i in [0,512))
// grid 512 blocks x 64 threads; block i handles row i.
__global__ void k_v2(const float* __restrict__ Lw2, const float* __restrict__ g2,
                     float* __restrict__ v2) {
    int i = blockIdx.x;
    int l = threadIdx.x;
    float acc = 0.f;
#pragma unroll
    for (int t = 0; t < 4; ++t) {
        int j = t * 64 + l;
        acc += Lw2[i * H2_ + j] * g2[j];
    }
#pragma unroll
    for (int off = 32; off >= 1; off >>= 1)
        acc += __shfl_xor(acc, off, 64);
    if (l == 0) v2[i] = acc * INV_;
}

// w_eff[k] = sum_i Lw1[k,i] * inv * g1[i] * v2[i]   (k in [0,624))
// grid 624 blocks x 256 threads.
__global__ void k_weff(const float* __restrict__ Lw1, const float* __restrict__ g1,
                       const float* __restrict__ v2, float* __restrict__ w_eff) {
    __shared__ float red[4];
    int k = blockIdx.x;
    int t = threadIdx.x;
    float acc = Lw1[k * H1_ + t]       * g1[t]       * v2[t]
              + Lw1[k * H1_ + t + 256] * g1[t + 256] * v2[t + 256];
#pragma unroll
    for (int off = 32; off >= 1; off >>= 1)
        acc += __shfl_xor(acc, off, 64);
    if ((t & 63) == 0) red[t >> 6] = acc;
    __syncthreads();
    if (t == 0)
        w_eff[k] = (red[0] + red[1] + red[2] + red[3]) * INV_;
}

// scalarC = sum_i (Lb1[i]*inv*g1[i] + be1[i]) * v2[i]
//         + sum_j (Lb2[j]*inv*g2[j] + be2[j])
// 1 block x 512 threads.
__global__ void k_scalar(const float* __restrict__ Lb1, const float* __restrict__ g1,
                         const float* __restrict__ be1, const float* __restrict__ v2,
                         const float* __restrict__ Lb2, const float* __restrict__ g2,
                         const float* __restrict__ be2, float* __restrict__ scalarC) {
    __shared__ float red[8];
    int t = threadIdx.x;
    float val = (Lb1[t] * INV_ * g1[t] + be1[t]) * v2[t];
    if (t < H2_)
        val += Lb2[t] * INV_ * g2[t] + be2[t];
#pragma unroll
    for (int off = 32; off >= 1; off >>= 1)
        val += __shfl_xor(val, off, 64);
    if ((t & 63) == 0) red[t >> 6] = val;
    __syncthreads();
    if (t == 0) {
        float s = 0.f;
#pragma unroll
        for (int w = 0; w < 8; ++w) s += red[w];
        scalarC[0] = s;
    }
}

// ---------------- main kernel ----------------
// 16 threads per batch row (one per embedding element e). Each sparse-field
// gather is a coalesced 64B quarter-wave transaction. Width-16 shuffle reduce.
__global__ void k_main(const int*   __restrict__ Xi,
                       const float* __restrict__ Xv,
                       const float* __restrict__ W1,  const float* __restrict__ b1,
                       const float* __restrict__ emb1,
                       const float* __restrict__ W2,  const float* __restrict__ b2,
                       const float* __restrict__ emb2,
                       const float* __restrict__ bias,
                       const float* __restrict__ w_eff,
                       const float* __restrict__ scalarC,
                       float* __restrict__ out) {
    int t = blockIdx.x * 256 + threadIdx.x;
    int b = t >> 4;
    int e = t & 15;

    const int*   xi_row = Xi + b * F_;
    const float* xv_row = Xv + b * F_;

    float accF = 0.f;   // fm_first partial
    float s1   = 0.f;   // sum_emb[e]
    float s2   = 0.f;   // sumsq[e]
    float accH = 0.f;   // h0 . w_eff partial

#pragma unroll
    for (int f = 0; f < FD_; ++f) {
        float xi  = (float)xi_row[f];
        float xv  = xv_row[f];
        float w1v = W1[f * E_ + e];
        float b1v = b1[f * E_ + e];
        float w2v = W2[f * E_ + e];
        float b2v = b2[f * E_ + e];
        float fl  = (xi * w1v + b1v) * xv;   // first_lin element
        float sec = xi * w2v + b2v;          // sec_lin element (no xv!)
        accF += fl;
        s1   += sec;
        s2   += sec * sec;
        accH += sec * w_eff[f * E_ + e];
    }

#pragma unroll
    for (int f = 0; f < FS_; ++f) {
        int   id = xi_row[FD_ + f];
        float xv = xv_row[FD_ + f];
        float e1 = emb1[(f * V_ + id) * E_ + e];
        float e2 = emb2[(f * V_ + id) * E_ + e];
        float sec = e2 * xv;                 // sec_emb element
        accF += e1 * xv;                     // first_emb element
        s1   += sec;
        s2   += sec * sec;
        accH += sec * w_eff[(FD_ + f) * E_ + e];
    }

    // per-element second-order term, then reduce across the 16 e-lanes
    float part = accF + accH + 0.5f * (s1 * s1 - s2);
    part += __shfl_xor(part, 8, 16);
    part += __shfl_xor(part, 4, 16);
    part += __shfl_xor(part, 2, 16);
    part += __shfl_xor(part, 1, 16);

    if (e == 0)
        out[b] = part + bias[b] + scalarC[0];
}

extern "C" void kernel_launch(void* const* d_in, const int* in_sizes, int n_in,
                              void* d_out, int out_size, void* d_ws, size_t ws_size,
                              hipStream_t stream) {
    const int*   Xi   = (const int*)  d_in[0];
    const float* Xv   = (const float*)d_in[1];
    const float* W1   = (const float*)d_in[2];
    const float* b1   = (const float*)d_in[3];
    const float* emb1 = (const float*)d_in[4];
    const float* W2   = (const float*)d_in[5];
    const float* b2   = (const float*)d_in[6];
    const float* emb2 = (const float*)d_in[7];
    const float* Lw1  = (const float*)d_in[8];
    const float* Lb1  = (const float*)d_in[9];
    const float* g1   = (const float*)d_in[10];
    const float* be1  = (const float*)d_in[11];
    const float* Lw2  = (const float*)d_in[12];
    const float* Lb2  = (const float*)d_in[13];
    const float* g2   = (const float*)d_in[14];
    const float* be2  = (const float*)d_in[15];
    const float* bias = (const float*)d_in[16];
    float* out = (float*)d_out;

    float* ws      = (float*)d_ws;
    float* v2      = ws;              // 512
    float* w_eff   = ws + 512;        // 624
    float* scalarC = ws + 512 + 624;  // 1

    k_v2    <<<H1_,  64, 0, stream>>>(Lw2, g2, v2);
    k_weff  <<<DIN_, 256, 0, stream>>>(Lw1, g1, v2, w_eff);
    k_scalar<<<1,    512, 0, stream>>>(Lb1, g1, be1, v2, Lb2, g2, be2, scalarC);
    k_main  <<<(B_ * E_) / 256, 256, 0, stream>>>(
        Xi, Xv, W1, b1, emb1, W2, b2, emb2, bias, w_eff, scalarC, out);
}